// Round 13
// baseline (37.781 us; speedup 1.0000x reference)
//
#include <hip/hip_runtime.h>
#include <math.h>

#define BB 32768
#define CC 8
#define HH 128
#define RR 16
#define GG 384
#define TT 32
#define NTILES (BB / TT + CC - 1)   // 1031 upper bound
#define MAXT2  (2 * NTILES)         // 2062 (each tile split into 2 col-halves)

// ---- workspace layout (bytes) ----
#define ROWS16_OFF 256
#define MBF_OFF   (ROWS16_OFF + CC * BB * 2)      // 256 + 512KB
#define COMB_OFF  (MBF_OFF + CC * GG * HH * 2)    // + 768KB
#define WS_NEEDED (COMB_OFF + CC * 4 * HH * 4)    // + 16KB  ~= 1.30 MB

typedef short short8 __attribute__((ext_vector_type(8)));
typedef float f32x4  __attribute__((ext_vector_type(4)));

__device__ __forceinline__ unsigned short f2bf(float f) {
    unsigned int u = __float_as_uint(f);
    return (unsigned short)((u + 0x7fffu + ((u >> 16) & 1u)) >> 16);
}
__device__ __forceinline__ float bf2f(unsigned short b) {
    return __uint_as_float(((unsigned int)b) << 16);
}
__device__ __forceinline__ float sigmoidf_fast(float v) { return 1.f / (1.f + __expf(-v)); }
__device__ __forceinline__ float tanhf_fast(float v)    { return 2.f / (1.f + __expf(-2.f * v)) - 1.f; }

// ---------------- pass 0: M_c = U_c @ V_c^T (bf16), comb table, zero cnt ----------------
// Mbf pairs: id in [0, CC*GG*HH/2): c = id/24576, g = (id%24576)>>6, j = (id&63)*2
// comb[c][gate][i]: gate0 = bih_r+bhh_r, 1 = bih_z+bhh_z, 2 = bhh_n, 3 = bih_n
__global__ __launch_bounds__(256) void prep_kernel(
    const float* __restrict__ U, const float* __restrict__ V,
    const float* __restrict__ bih, const float* __restrict__ bhh,
    unsigned int* __restrict__ Mbf_u32, float* __restrict__ comb,
    int* __restrict__ cnt)
{
    const int id = blockIdx.x * 256 + threadIdx.x;
    if (blockIdx.x == 0 && threadIdx.x < CC) cnt[threadIdx.x] = 0;

    const int NM2 = CC * GG * HH / 2;   // 196608
    if (id < NM2) {
        const int c   = id / (GG * HH / 2);
        const int rem = id % (GG * HH / 2);
        const int g   = rem >> 6;
        const int j   = (rem & 63) * 2;
        const float* Up  = U + ((size_t)c * GG + g) * RR;
        const float* Vp0 = V + ((size_t)c * HH + j) * RR;
        const float* Vp1 = Vp0 + RR;
        float s0 = 0.f, s1 = 0.f;
        #pragma unroll
        for (int r = 0; r < RR; ++r) {
            const float u = Up[r];
            s0 += u * Vp0[r];
            s1 += u * Vp1[r];
        }
        Mbf_u32[id] = (unsigned int)f2bf(s0) | ((unsigned int)f2bf(s1) << 16);
    } else if (id < NM2 + CC * 4 * HH) {
        const int e = id - NM2;            // 0..4095
        const int c = e >> 9, s = e & 511;
        const int gate = s >> 7, i = s & 127;
        float v;
        if      (gate == 0) v = bih[c * GG + i]       + bhh[c * GG + i];
        else if (gate == 1) v = bih[c * GG + 128 + i] + bhh[c * GG + 128 + i];
        else if (gate == 2) v = bhh[c * GG + 256 + i];
        else                v = bih[c * GG + 256 + i];
        comb[e] = v;
    }
}

// ---------------- pass 1: bucket rows by condition (ushort indices) ----------------
__global__ __launch_bounds__(256) void bucket_kernel(
    const float* __restrict__ x, int* __restrict__ cnt,
    unsigned short* __restrict__ rows16)
{
    __shared__ int lcnt[CC];
    __shared__ int lbase[CC];
    const int tid = threadIdx.x;
    const int b = blockIdx.x * 256 + tid;

    if (tid < CC) lcnt[tid] = 0;
    __syncthreads();

    const float4 x0 = *(const float4*)(x + (size_t)b * CC);
    const float4 x1 = *(const float4*)(x + (size_t)b * CC + 4);
    int c = 0;
    if      (x0.x != 0.f) c = 0;
    else if (x0.y != 0.f) c = 1;
    else if (x0.z != 0.f) c = 2;
    else if (x0.w != 0.f) c = 3;
    else if (x1.x != 0.f) c = 4;
    else if (x1.y != 0.f) c = 5;
    else if (x1.z != 0.f) c = 6;
    else if (x1.w != 0.f) c = 7;

    const int mypos = atomicAdd(&lcnt[c], 1);
    __syncthreads();
    if (tid < CC) lbase[tid] = atomicAdd(&cnt[tid], lcnt[tid]);
    __syncthreads();
    rows16[c * BB + lbase[c] + mypos] = (unsigned short)b;
}

// ---------------- pass 2: bucketed single-GEMM GRU ----------------
// Block = (tile of 32 same-condition rows) x (column half of 64).
// gates[32 x 384-half] = h[32x128] @ M_c^T ; epilogue with broadcast comb.
__global__ __launch_bounds__(256) void gru_m_kernel(
    const float* __restrict__ x, const float* __restrict__ h,
    const unsigned short* __restrict__ Mbf, const float* __restrict__ comb_g,
    const unsigned short* __restrict__ rows16, const int* __restrict__ cnt,
    float* __restrict__ out)
{
    // tile descriptor
    int ncs[CC], tcs[CC];
    #pragma unroll
    for (int q = 0; q < CC; ++q) { ncs[q] = cnt[q]; tcs[q] = (ncs[q] + TT - 1) / TT; }
    const int tile = blockIdx.x >> 1;
    const int half = blockIdx.x & 1;
    int c = -1, start = 0, nc = 0, base = 0;
    #pragma unroll
    for (int q = 0; q < CC; ++q) {
        if (c < 0 && tile < base + tcs[q]) { c = q; start = (tile - base) * TT; nc = ncs[q]; }
        base += tcs[q];
    }
    if (c < 0) return;

    __shared__ __align__(16) unsigned short hs[TT][HH + 8];  // 8.7 KB, 272B stride
    __shared__ float comb_s[512];                             // 2 KB (uniform c)
    __shared__ int   rloc[TT];
    __shared__ float wloc[TT];

    const int tid  = threadIdx.x;
    const int w    = tid >> 6;
    const int lane = tid & 63;
    const int r16  = lane & 15;
    const int hi   = lane >> 4;

    // stage h rows (gathered, 512B burst per row; bf16)
    {
        const int row = tid >> 3, seg = tid & 7;
        const int idx = start + row;
        const int b = (idx < nc) ? (int)rows16[c * BB + idx] : -1;
        short8 o0 = {0,0,0,0,0,0,0,0}, o1 = {0,0,0,0,0,0,0,0};
        if (b >= 0) {
            const float* hp = h + (size_t)b * HH + seg * 16;
            const float4 a0 = *(const float4*)(hp + 0);
            const float4 a1 = *(const float4*)(hp + 4);
            const float4 a2 = *(const float4*)(hp + 8);
            const float4 a3 = *(const float4*)(hp + 12);
            o0[0]=(short)f2bf(a0.x); o0[1]=(short)f2bf(a0.y); o0[2]=(short)f2bf(a0.z); o0[3]=(short)f2bf(a0.w);
            o0[4]=(short)f2bf(a1.x); o0[5]=(short)f2bf(a1.y); o0[6]=(short)f2bf(a1.z); o0[7]=(short)f2bf(a1.w);
            o1[0]=(short)f2bf(a2.x); o1[1]=(short)f2bf(a2.y); o1[2]=(short)f2bf(a2.z); o1[3]=(short)f2bf(a2.w);
            o1[4]=(short)f2bf(a3.x); o1[5]=(short)f2bf(a3.y); o1[6]=(short)f2bf(a3.z); o1[7]=(short)f2bf(a3.w);
        }
        *(short8*)&hs[row][seg * 16]     = o0;
        *(short8*)&hs[row][seg * 16 + 8] = o1;
    }
    if (tid < TT) {
        const int idx = start + tid;
        const int b = (idx < nc) ? (int)rows16[c * BB + idx] : -1;
        rloc[tid] = b;
        wloc[tid] = (b >= 0) ? x[(size_t)b * CC + c] : 0.f;
    }
    comb_s[tid]       = comb_g[c * 512 + tid];
    comb_s[256 + tid] = comb_g[c * 512 + 256 + tid];
    __syncthreads();

    // A-fragments (reused across all gate tiles)
    short8 az[2][4];
    #pragma unroll
    for (int mt = 0; mt < 2; ++mt)
        #pragma unroll
        for (int ks = 0; ks < 4; ++ks)
            az[mt][ks] = *(const short8*)&hs[mt * 16 + r16][ks * 32 + hi * 8];

    // GEMM: this wave owns i-columns [half*64 + w*16, +16), all 3 gates
    const unsigned short* Mc = Mbf + (size_t)c * GG * HH;
    const int colb = half * 64 + w * 16 + r16;   // output feature i
    f32x4 aR[2] = {{0,0,0,0},{0,0,0,0}};
    f32x4 aZ[2] = {{0,0,0,0},{0,0,0,0}};
    f32x4 aN[2] = {{0,0,0,0},{0,0,0,0}};
    #pragma unroll
    for (int ks = 0; ks < 4; ++ks) {
        const short8 bR = *(const short8*)(Mc + (size_t)(0 * HH + colb) * HH + ks * 32 + hi * 8);
        const short8 bZ = *(const short8*)(Mc + (size_t)(1 * HH + colb) * HH + ks * 32 + hi * 8);
        const short8 bN = *(const short8*)(Mc + (size_t)(2 * HH + colb) * HH + ks * 32 + hi * 8);
        #pragma unroll
        for (int mt = 0; mt < 2; ++mt) {
            aR[mt] = __builtin_amdgcn_mfma_f32_16x16x32_bf16(az[mt][ks], bR, aR[mt], 0, 0, 0);
            aZ[mt] = __builtin_amdgcn_mfma_f32_16x16x32_bf16(az[mt][ks], bZ, aZ[mt], 0, 0, 0);
            aN[mt] = __builtin_amdgcn_mfma_f32_16x16x32_bf16(az[mt][ks], bN, aN[mt], 0, 0, 0);
        }
    }

    // epilogue: comb values are per-lane scalars (broadcast LDS reads)
    const int i = colb;
    const float cbr  = comb_s[i];
    const float cbz  = comb_s[128 + i];
    const float cbnh = comb_s[256 + i];
    const float cbni = comb_s[384 + i];
    #pragma unroll
    for (int mt = 0; mt < 2; ++mt) {
        #pragma unroll
        for (int q = 0; q < 4; ++q) {
            const int row = mt * 16 + 4 * hi + q;
            const int b   = rloc[row];
            const float wv = wloc[row];
            const float rg = sigmoidf_fast(aR[mt][q] + wv * cbr);
            const float zg = sigmoidf_fast(aZ[mt][q] + wv * cbz);
            const float ng = tanhf_fast(wv * cbni + rg * (aN[mt][q] + wv * cbnh));
            const float hv = bf2f(hs[row][i]);
            if (b >= 0)
                out[(size_t)b * HH + i] = (1.f - zg) * ng + zg * hv;
        }
    }
}

// ---------------- fallback if ws too small ----------------
__global__ __launch_bounds__(128) void gru_cell_naive(
    const float* __restrict__ x, const float* __restrict__ h,
    const float* __restrict__ U, const float* __restrict__ V,
    const float* __restrict__ bias_ih, const float* __restrict__ bias_hh,
    float* __restrict__ out)
{
    const int b = blockIdx.x;
    const int i = threadIdx.x;
    __shared__ float hsn[HH];
    __shared__ float xsn[CC];
    __shared__ float vhn[RR];
    const float h_i = h[b * HH + i];
    hsn[i] = h_i;
    if (i < CC) xsn[i] = x[b * CC + i];
    __syncthreads();
    float g_r = 0.f, g_z = 0.f, g_n = 0.f;
    float bi_r = 0.f, bi_z = 0.f, bi_n = 0.f;
    float bh_r = 0.f, bh_z = 0.f, bh_n = 0.f;
    for (int c = 0; c < CC; ++c) {
        const float w = xsn[c];
        if (w != 0.f) {
            if (i < RR) {
                const float* Vp = V + c * HH * RR + i;
                float a0 = 0.f;
                for (int j = 0; j < HH; ++j) a0 += Vp[j * RR] * hsn[j];
                vhn[i] = a0;
            }
            __syncthreads();
            const float* Up = U + c * 3 * HH * RR;
            float s_r = 0.f, s_z = 0.f, s_n = 0.f;
            for (int r = 0; r < RR; ++r) s_r += Up[i * RR + r] * vhn[r];
            for (int r = 0; r < RR; ++r) s_z += Up[(HH + i) * RR + r] * vhn[r];
            for (int r = 0; r < RR; ++r) s_n += Up[(2 * HH + i) * RR + r] * vhn[r];
            g_r += w * s_r; g_z += w * s_z; g_n += w * s_n;
            bi_r += w * bias_ih[c * GG + i];
            bi_z += w * bias_ih[c * GG + HH + i];
            bi_n += w * bias_ih[c * GG + 2 * HH + i];
            bh_r += w * bias_hh[c * GG + i];
            bh_z += w * bias_hh[c * GG + HH + i];
            bh_n += w * bias_hh[c * GG + 2 * HH + i];
            __syncthreads();
        }
    }
    const float rg = 1.f / (1.f + __expf(-(bi_r + g_r + bh_r)));
    const float zg = 1.f / (1.f + __expf(-(bi_z + g_z + bh_z)));
    const float ng = tanhf(bi_n + rg * (g_n + bh_n));
    out[b * HH + i] = (1.f - zg) * ng + zg * h_i;
}

extern "C" void kernel_launch(void* const* d_in, const int* in_sizes, int n_in,
                              void* d_out, int out_size, void* d_ws, size_t ws_size,
                              hipStream_t stream) {
    const float* x       = (const float*)d_in[0];
    const float* h       = (const float*)d_in[1];
    const float* U       = (const float*)d_in[2];
    const float* V       = (const float*)d_in[3];
    const float* bias_ih = (const float*)d_in[4];
    const float* bias_hh = (const float*)d_in[5];
    float* out = (float*)d_out;

    if (ws_size < (size_t)WS_NEEDED) {
        gru_cell_naive<<<BB, HH, 0, stream>>>(x, h, U, V, bias_ih, bias_hh, out);
        return;
    }

    int*            cnt    = (int*)d_ws;
    unsigned short* rows16 = (unsigned short*)((char*)d_ws + ROWS16_OFF);
    unsigned short* Mbf    = (unsigned short*)((char*)d_ws + MBF_OFF);
    float*          comb   = (float*)((char*)d_ws + COMB_OFF);

    const int prep_elems = CC * GG * HH / 2 + CC * 4 * HH;   // 200704
    prep_kernel<<<(prep_elems + 255) / 256, 256, 0, stream>>>(
        U, V, bias_ih, bias_hh, (unsigned int*)Mbf, comb, cnt);
    bucket_kernel<<<BB / 256, 256, 0, stream>>>(x, cnt, rows16);
    gru_m_kernel<<<MAXT2, 256, 0, stream>>>(x, h, Mbf, comb, rows16, cnt, out);
}